// Round 1
// baseline (171.489 us; speedup 1.0000x reference)
//
#include <hip/hip_runtime.h>

typedef _Float16 half8 __attribute__((ext_vector_type(8)));
typedef _Float16 half4_t __attribute__((ext_vector_type(4)));
typedef float floatx4 __attribute__((ext_vector_type(4)));

#define LP 136  // LDS row pitch in halves: 128 + 8 pad -> 272B rows, 16B-aligned, conflict-free b128

// Repack W1 (cols 1..128, fp16) and W2 (fp16) into MFMA A-fragment order:
// chunk c = mtile*4+kb, lane L, jj: element [mtile*16+(L&15)][kb*32+(L>>4)*8+jj]
__global__ __launch_bounds__(256) void repack_weights(
    const float* __restrict__ W1, const float* __restrict__ W2,
    _Float16* __restrict__ wsh)
{
    int tid = blockIdx.x * 256 + threadIdx.x;
    if (tid < 16384) {                    // W1: 8 mtiles x 4 kb x 512
        int c = tid >> 9, r = tid & 511;
        int L = r >> 3, jj = r & 7;
        int mt = c >> 2, kb = c & 3;
        int n = mt * 16 + (L & 15);
        int k = kb * 32 + (L >> 4) * 8 + jj;
        wsh[tid] = (_Float16)W1[n * 129 + 1 + k];
    } else if (tid < 24576) {             // W2: 4 mtiles x 4 kb x 512
        int t = tid - 16384;
        int c = t >> 9, r = t & 511;
        int L = r >> 3, jj = r & 7;
        int mt = c >> 2, kb = c & 3;
        int i = mt * 16 + (L & 15);
        int j = kb * 32 + (L >> 4) * 8 + jj;
        wsh[tid] = (_Float16)W2[i * 128 + j];
    }
}

__global__ __launch_bounds__(256, 2) void edge_mlp_kernel(
    const float* __restrict__ x,
    const int* __restrict__ ei,
    const float* __restrict__ ew,
    const float* __restrict__ W1, const float* __restrict__ b1,
    const float* __restrict__ b2,
    const float* __restrict__ W3, const float* __restrict__ b3,
    const _Float16* __restrict__ wf,
    float* __restrict__ out, int E)
{
    __shared__ __align__(16) _Float16 hA[64 * LP];   // [edge][k] fp16 features
    __shared__ __align__(16) _Float16 h1A[64 * LP];  // [edge][n] fp16 hidden1
    __shared__ float s_ew[64];
    __shared__ float s_b1[128];
    __shared__ float s_c0[128];   // W1[:,0] (edge-weight column)
    __shared__ float s_b2[64];
    __shared__ float s_w3[64];
    __shared__ float s_out[4][64];

    const int tid = threadIdx.x;
    const int e_blk = blockIdx.x * 64;

    // ---- stage small uniform arrays ----
    if (tid < 128) { s_b1[tid] = b1[tid]; s_c0[tid] = W1[tid * 129]; }
    else if (tid < 192) { int i = tid - 128; s_b2[i] = b2[i]; s_w3[i] = W3[i]; }
    if (tid < 64) {
        int e = e_blk + tid; if (e >= E) e = E - 1;
        s_ew[tid] = ew[e];
    }

    // ---- gather node features -> hA (fp16): k 0..63 = src, 64..127 = tgt ----
    {
        int e_loc = tid >> 2;
        int part = tid & 3;                 // 0,1: src halves; 2,3: tgt halves
        int e = e_blk + e_loc; if (e >= E) e = E - 1;
        int nsrc = ei[e];
        int ntgt = ei[E + e];
        const float* rowp = (part < 2) ? (x + (long long)nsrc * 64)
                                       : (x + (long long)ntgt * 64);
        const float* pp = rowp + (part & 1) * 32;
        _Float16* dst = &hA[e_loc * LP + part * 32];
#pragma unroll
        for (int q = 0; q < 8; ++q) {
            float4 v = *(const float4*)(pp + q * 4);
            half4_t h = { (_Float16)v.x, (_Float16)v.y, (_Float16)v.z, (_Float16)v.w };
            *(half4_t*)(dst + q * 4) = h;
        }
    }
    __syncthreads();

    const int lane = tid & 63;
    const int wave = tid >> 6;
    const int lrow = lane & 15;
    const int quad = lane >> 4;

    // ---- layer 1: D1T[n][e] = W1h(128x128k) x hA^T(128k x 64e) ----
    // wave handles n-tiles {2*wave, 2*wave+1}, all 4 e-tiles, K=128 (4 ksteps)
    half8 bfr[4][4];
#pragma unroll
    for (int nt = 0; nt < 4; ++nt)
#pragma unroll
        for (int kb = 0; kb < 4; ++kb)
            bfr[nt][kb] = *(const half8*)(&hA[(nt * 16 + lrow) * LP + kb * 32 + quad * 8]);

    floatx4 acc1[2][4];
#pragma unroll
    for (int mi = 0; mi < 2; ++mi) {
        half8 afr[4];
#pragma unroll
        for (int kb = 0; kb < 4; ++kb)
            afr[kb] = *(const half8*)(wf + ((2 * wave + mi) * 4 + kb) * 512 + lane * 8);
#pragma unroll
        for (int nt = 0; nt < 4; ++nt) {
            floatx4 a = {0.f, 0.f, 0.f, 0.f};
#pragma unroll
            for (int kb = 0; kb < 4; ++kb)
                a = __builtin_amdgcn_mfma_f32_16x16x32_f16(afr[kb], bfr[nt][kb], a, 0, 0, 0);
            acc1[mi][nt] = a;
        }
    }

    // epilogue: + b1 + ew*W1[:,0], relu, pack 4 halves -> h1A[e][n]
#pragma unroll
    for (int mi = 0; mi < 2; ++mi) {
        int nb = (2 * wave + mi) * 16 + quad * 4;
#pragma unroll
        for (int nt = 0; nt < 4; ++nt) {
            int e = nt * 16 + lrow;
            float ewv = s_ew[e];
            half4_t hv;
#pragma unroll
            for (int r = 0; r < 4; ++r) {
                float v = acc1[mi][nt][r] + s_b1[nb + r] + ewv * s_c0[nb + r];
                v = fmaxf(v, 0.f);
                hv[r] = (_Float16)v;
            }
            *(half4_t*)(&h1A[e * LP + nb]) = hv;
        }
    }
    __syncthreads();

    // ---- layer 2: D2T[i][e] = W2h(64x128j) x h1^T ; wave handles i-tile = wave ----
    half8 b2fr[4][4];
#pragma unroll
    for (int nt = 0; nt < 4; ++nt)
#pragma unroll
        for (int kb = 0; kb < 4; ++kb)
            b2fr[nt][kb] = *(const half8*)(&h1A[(nt * 16 + lrow) * LP + kb * 32 + quad * 8]);

    half8 a2fr[4];
#pragma unroll
    for (int kb = 0; kb < 4; ++kb)
        a2fr[kb] = *(const half8*)(wf + 16384 + (wave * 4 + kb) * 512 + lane * 8);

#pragma unroll
    for (int nt = 0; nt < 4; ++nt) {
        floatx4 a = {0.f, 0.f, 0.f, 0.f};
#pragma unroll
        for (int kb = 0; kb < 4; ++kb)
            a = __builtin_amdgcn_mfma_f32_16x16x32_f16(a2fr[kb], b2fr[nt][kb], a, 0, 0, 0);
        // layer-2 epilogue (bias+relu) fused with layer-3 dot against W3
        int ib = wave * 16 + quad * 4;
        float p = 0.f;
#pragma unroll
        for (int r = 0; r < 4; ++r) {
            float v = a[r] + s_b2[ib + r];
            v = fmaxf(v, 0.f);
            p += v * s_w3[ib + r];
        }
        p += __shfl_xor(p, 16, 64);   // reduce across quads (i within wave's 16)
        p += __shfl_xor(p, 32, 64);
        if (quad == 0) s_out[wave][nt * 16 + lrow] = p;
    }
    __syncthreads();

    if (tid < 64) {
        int oe = e_blk + tid;
        if (oe < E)
            out[oe] = b3[0] + s_out[0][tid] + s_out[1][tid]
                            + s_out[2][tid] + s_out[3][tid];
    }
}

extern "C" void kernel_launch(void* const* d_in, const int* in_sizes, int n_in,
                              void* d_out, int out_size, void* d_ws, size_t ws_size,
                              hipStream_t stream) {
    const float* x  = (const float*)d_in[0];
    const int*   ei = (const int*)d_in[1];   // JAX x64-disabled -> int32
    const float* ew = (const float*)d_in[2];
    const float* W1 = (const float*)d_in[3];
    const float* b1 = (const float*)d_in[4];
    const float* W2 = (const float*)d_in[5];
    const float* b2 = (const float*)d_in[6];
    const float* W3 = (const float*)d_in[7];
    const float* b3 = (const float*)d_in[8];
    float* out = (float*)d_out;
    const int E = in_sizes[2];               // edge_weight element count = n_edges
    _Float16* wsh = (_Float16*)d_ws;         // needs 48 KiB

    repack_weights<<<96, 256, 0, stream>>>(W1, W2, wsh);
    int nblk = (E + 63) / 64;
    edge_mlp_kernel<<<nblk, 256, 0, stream>>>(x, ei, ew, W1, b1, b2, W3, b3,
                                              wsh, out, E);
}

// Round 2
// 141.406 us; speedup vs baseline: 1.2127x; 1.2127x over previous
//
#include <hip/hip_runtime.h>

typedef _Float16 half8 __attribute__((ext_vector_type(8)));
typedef _Float16 half4_t __attribute__((ext_vector_type(4)));
typedef float floatx4 __attribute__((ext_vector_type(4)));

#define LP 136  // LDS row pitch in halves: 128 + 8 pad -> 272B rows, 16B-aligned

// One prep kernel: blocks [0,96) repack W1/W2 to MFMA A-frag order (fp16),
// blocks [96,..) convert x to fp16 (xh = L2-resident 6.4 MB copy).
__global__ __launch_bounds__(256) void prep_kernel(
    const float* __restrict__ x,
    const float* __restrict__ W1, const float* __restrict__ W2,
    _Float16* __restrict__ wsh, _Float16* __restrict__ xh, int n_x8)
{
    int b = blockIdx.x;
    if (b < 96) {
        int tid = b * 256 + threadIdx.x;
        if (tid < 16384) {                    // W1 cols 1..128: 8 mtiles x 4 kb x 512
            int c = tid >> 9, r = tid & 511;
            int L = r >> 3, jj = r & 7;
            int mt = c >> 2, kb = c & 3;
            int n = mt * 16 + (L & 15);
            int k = kb * 32 + (L >> 4) * 8 + jj;
            wsh[tid] = (_Float16)W1[n * 129 + 1 + k];
        } else {                              // W2: 4 mtiles x 4 kb x 512
            int t = tid - 16384;
            int c = t >> 9, r = t & 511;
            int L = r >> 3, jj = r & 7;
            int mt = c >> 2, kb = c & 3;
            int i = mt * 16 + (L & 15);
            int j = kb * 32 + (L >> 4) * 8 + jj;
            wsh[tid] = (_Float16)W2[i * 128 + j];
        }
    } else {
        int t2 = (b - 96) * 256 + threadIdx.x;
        if (t2 < n_x8) {
            const float4* p = (const float4*)(x + (size_t)t2 * 8);
            float4 v0 = p[0], v1 = p[1];
            half8 h = {(_Float16)v0.x, (_Float16)v0.y, (_Float16)v0.z, (_Float16)v0.w,
                       (_Float16)v1.x, (_Float16)v1.y, (_Float16)v1.z, (_Float16)v1.w};
            *(half8*)(xh + (size_t)t2 * 8) = h;
        }
    }
}

__global__ __launch_bounds__(256, 4) void edge_mlp_kernel(
    const _Float16* __restrict__ xh,
    const int* __restrict__ ei,
    const float* __restrict__ ew,
    const float* __restrict__ W1, const float* __restrict__ b1,
    const float* __restrict__ b2,
    const float* __restrict__ W3, const float* __restrict__ b3,
    const _Float16* __restrict__ wf,
    float* __restrict__ out, int E)
{
    // hA holds [edge][k] fp16 features for layer 1; after a full barrier it is
    // REUSED as [edge][n] hidden-1 storage (all reads complete before writes).
    __shared__ __align__(16) _Float16 hA[128 * LP];
    __shared__ float s_ew[128];
    __shared__ float s_b1[128];
    __shared__ float s_c0[128];   // W1[:,0] (edge-weight column, rank-1 epilogue)
    __shared__ float s_b2[64];
    __shared__ float s_w3[64];
    __shared__ float s_out[4][128];

    const int tid = threadIdx.x;
    const int e_blk = blockIdx.x * 128;

    if (tid < 128) {
        s_b1[tid] = b1[tid];
        s_c0[tid] = W1[tid * 129];
        int e = e_blk + tid; if (e >= E) e = E - 1;
        s_ew[tid] = ew[e];
    } else if (tid < 192) {
        int i = tid - 128;
        s_b2[i] = b2[i];
        s_w3[i] = W3[i];
    }

    // ---- gather fp16 node rows -> hA: k 0..63 = src, 64..127 = tgt ----
    {
        int e_loc = tid >> 1;
        int part = tid & 1;
        int e = e_blk + e_loc; if (e >= E) e = E - 1;
        int node = ei[(size_t)part * E + e];
        const _Float16* rp = xh + (size_t)node * 64;
        _Float16* dst = &hA[e_loc * LP + part * 64];
#pragma unroll
        for (int q = 0; q < 8; ++q)
            *(half8*)(dst + q * 8) = *(const half8*)(rp + q * 8);
    }
    __syncthreads();

    const int lane = tid & 63;
    const int wave = tid >> 6;
    const int lrow = lane & 15;
    const int quad = lane >> 4;

    // ---- layer 1: D1T[n][e] = W1h(128n x 128k) x hA^T(128k x 128e) ----
    half8 afr[2][4];
#pragma unroll
    for (int mi = 0; mi < 2; ++mi)
#pragma unroll
        for (int kb = 0; kb < 4; ++kb)
            afr[mi][kb] = *(const half8*)(wf + ((2 * wave + mi) * 4 + kb) * 512 + lane * 8);

    half4_t h1v[2][8];
#pragma unroll
    for (int nt = 0; nt < 8; ++nt) {
        half8 bfr[4];
#pragma unroll
        for (int kb = 0; kb < 4; ++kb)
            bfr[kb] = *(const half8*)(&hA[(nt * 16 + lrow) * LP + kb * 32 + quad * 8]);
        float ewv = s_ew[nt * 16 + lrow];
#pragma unroll
        for (int mi = 0; mi < 2; ++mi) {
            floatx4 a = {0.f, 0.f, 0.f, 0.f};
#pragma unroll
            for (int kb = 0; kb < 4; ++kb)
                a = __builtin_amdgcn_mfma_f32_16x16x32_f16(afr[mi][kb], bfr[kb], a, 0, 0, 0);
            int nb = (2 * wave + mi) * 16 + quad * 4;
            half4_t hv;
#pragma unroll
            for (int r = 0; r < 4; ++r) {
                float v = a[r] + s_b1[nb + r] + ewv * s_c0[nb + r];
                hv[r] = (_Float16)fmaxf(v, 0.f);
            }
            h1v[mi][nt] = hv;
        }
    }
    __syncthreads();   // all hA feature reads complete — safe to alias

    // ---- write hidden1 (fp16) into hA space as [e][n] ----
#pragma unroll
    for (int mi = 0; mi < 2; ++mi) {
        int nb = (2 * wave + mi) * 16 + quad * 4;
#pragma unroll
        for (int nt = 0; nt < 8; ++nt)
            *(half4_t*)(&hA[(nt * 16 + lrow) * LP + nb]) = h1v[mi][nt];
    }
    __syncthreads();

    // ---- layer 2 (+fused layer 3): wave handles i-tile = wave ----
    half8 a2fr[4];
#pragma unroll
    for (int kb = 0; kb < 4; ++kb)
        a2fr[kb] = *(const half8*)(wf + 16384 + (wave * 4 + kb) * 512 + lane * 8);

#pragma unroll
    for (int nt = 0; nt < 8; ++nt) {
        half8 bfr[4];
#pragma unroll
        for (int kb = 0; kb < 4; ++kb)
            bfr[kb] = *(const half8*)(&hA[(nt * 16 + lrow) * LP + kb * 32 + quad * 8]);
        floatx4 a = {0.f, 0.f, 0.f, 0.f};
#pragma unroll
        for (int kb = 0; kb < 4; ++kb)
            a = __builtin_amdgcn_mfma_f32_16x16x32_f16(a2fr[kb], bfr[kb], a, 0, 0, 0);
        int ib = wave * 16 + quad * 4;
        float p = 0.f;
#pragma unroll
        for (int r = 0; r < 4; ++r)
            p += fmaxf(a[r] + s_b2[ib + r], 0.f) * s_w3[ib + r];
        p += __shfl_xor(p, 16, 64);
        p += __shfl_xor(p, 32, 64);
        if (quad == 0) s_out[wave][nt * 16 + lrow] = p;
    }
    __syncthreads();

    if (tid < 128) {
        int oe = e_blk + tid;
        if (oe < E)
            out[oe] = b3[0] + s_out[0][tid] + s_out[1][tid]
                            + s_out[2][tid] + s_out[3][tid];
    }
}

extern "C" void kernel_launch(void* const* d_in, const int* in_sizes, int n_in,
                              void* d_out, int out_size, void* d_ws, size_t ws_size,
                              hipStream_t stream) {
    const float* x  = (const float*)d_in[0];
    const int*   ei = (const int*)d_in[1];   // int32 (verified round 1)
    const float* ew = (const float*)d_in[2];
    const float* W1 = (const float*)d_in[3];
    const float* b1 = (const float*)d_in[4];
    const float* W2 = (const float*)d_in[5];
    const float* b2 = (const float*)d_in[6];
    const float* W3 = (const float*)d_in[7];
    const float* b3 = (const float*)d_in[8];
    float* out = (float*)d_out;
    const int E = in_sizes[2];               // n_edges
    const int n_x = in_sizes[0];             // 3.2M floats
    const int n_x8 = n_x / 8;

    _Float16* wsh = (_Float16*)d_ws;                 // 24576 halves = 48 KiB
    _Float16* xh  = (_Float16*)((char*)d_ws + 49152); // fp16 x copy, 6.4 MB

    int xblk = (n_x8 + 255) / 256;
    prep_kernel<<<96 + xblk, 256, 0, stream>>>(x, W1, W2, wsh, xh, n_x8);

    int nblk = (E + 127) / 128;
    edge_mlp_kernel<<<nblk, 256, 0, stream>>>(xh, ei, ew, W1, b1, b2, W3, b3,
                                              wsh, out, E);
}